// Round 1
// baseline (1581.412 us; speedup 1.0000x reference)
//
#include <hip/hip_runtime.h>
#include <math.h>

// Problem constants
constexpr int BB  = 64;    // batch
constexpr int CIc = 3;     // image channels
constexpr int HIc = 96, WIc = 96;
constexpr int Gc  = 8, HGc = 16, WGc = 16;
constexpr int HIDc = 18432;      // 128*12*12
constexpr int HIDLINc = 512;

// ---------------------------------------------------------------------------
// Direct 3x3 conv (pad=1, stride=1) + bias + ReLU.
// Each block: one (batch, spatial tile, 32-output-channel chunk).
// Input tile (with halo) staged in LDS in CBLK-channel chunks.
// Each thread: one output pixel, 32 output-channel accumulators in registers.
// Weight addresses are wave-uniform -> compiler emits scalar loads (s_load),
// so the inner loop is ~9 ds_read + 288 v_fma per input channel.
// ---------------------------------------------------------------------------
template<int CIN, int COUT, int H, int W, int TH, int TW, int CBLK>
__global__ __launch_bounds__(TH * TW)
void conv3x3_relu(const float* __restrict__ in, const float* __restrict__ wgt,
                  const float* __restrict__ bias, float* __restrict__ out)
{
    constexpr int NTX = W / TW;
    const int tile = blockIdx.x;
    const int tx = tile % NTX, ty = tile / NTX;
    const int b  = blockIdx.y;
    const int coutBase = blockIdx.z * 32;
    const int tid = threadIdx.x;
    const int px = tid % TW, py = tid / TW;
    const int ox = tx * TW, oy = ty * TH;

    __shared__ float s_in[CBLK][TH + 2][TW + 2];

    float acc[32];
#pragma unroll
    for (int oc = 0; oc < 32; ++oc) acc[oc] = bias[coutBase + oc];

    for (int cb = 0; cb < CIN; cb += CBLK) {
        __syncthreads();
        constexpr int TOT = CBLK * (TH + 2) * (TW + 2);
        for (int idx = tid; idx < TOT; idx += TH * TW) {
            int ci  = idx / ((TH + 2) * (TW + 2));
            int rem = idx % ((TH + 2) * (TW + 2));
            int yy = rem / (TW + 2), xx = rem % (TW + 2);
            int gy = oy + yy - 1, gx = ox + xx - 1;
            float v = 0.0f;
            if (gy >= 0 && gy < H && gx >= 0 && gx < W)
                v = in[((size_t)(b * CIN + cb + ci) * H + gy) * W + gx];
            s_in[ci][yy][xx] = v;
        }
        __syncthreads();

        for (int ci = 0; ci < CBLK; ++ci) {
            float v[9];
#pragma unroll
            for (int dy = 0; dy < 3; ++dy)
#pragma unroll
                for (int dx = 0; dx < 3; ++dx)
                    v[dy * 3 + dx] = s_in[ci][py + dy][px + dx];

#pragma unroll
            for (int oc = 0; oc < 32; ++oc) {
                const float* w9 =
                    wgt + ((size_t)(coutBase + oc) * CIN + (cb + ci)) * 9;
#pragma unroll
                for (int k = 0; k < 9; ++k)
                    acc[oc] = fmaf(v[k], w9[k], acc[oc]);
            }
        }
    }

#pragma unroll
    for (int oc = 0; oc < 32; ++oc) {
        out[((size_t)(b * COUT + coutBase + oc) * H + oy + py) * W + ox + px] =
            fmaxf(acc[oc], 0.0f);
    }
}

// ---------------------------------------------------------------------------
// Max pool KxK, stride K
// ---------------------------------------------------------------------------
template<int C, int H, int W, int K>
__global__ void maxpool_k(const float* __restrict__ in, float* __restrict__ out)
{
    constexpr int HO = H / K, WO = W / K;
    int idx = blockIdx.x * blockDim.x + threadIdx.x;
    constexpr int TOTAL = BB * C * HO * WO;
    if (idx >= TOTAL) return;
    int wo = idx % WO; int t = idx / WO;
    int ho = t % HO; t /= HO;
    int c = t % C; int b = t / C;
    const float* p = in + ((size_t)(b * C + c) * H + ho * K) * W + wo * K;
    float m = -INFINITY;
#pragma unroll
    for (int i = 0; i < K; ++i)
#pragma unroll
        for (int j = 0; j < K; ++j)
            m = fmaxf(m, p[i * W + j]);
    out[idx] = m;
}

// ---------------------------------------------------------------------------
// lin1: (64, 18432) @ (18432, 512), split-K partials.
// grid = (8 j-tiles, 64 k-splits); block 256 = 64 j-lanes x 4 b-groups.
// Each thread: 16 batch accumulators; x chunk staged transposed in LDS so the
// 16 x-values per step come from 4 ds_read_b128.
// ---------------------------------------------------------------------------
constexpr int KSPLIT = 64;              // 18432 / 64 = 288 per split
__global__ __launch_bounds__(256)
void lin1_partial(const float* __restrict__ x, const float* __restrict__ w,
                  float* __restrict__ partial)
{
    const int j  = threadIdx.x % 64;
    const int bg = threadIdx.x / 64;          // 0..3
    const int jBase = blockIdx.x * 64;        // 8 tiles of 64
    const int k  = blockIdx.y;                // 0..63
    const int i0 = k * 288;

    __shared__ float s_x[32][64];

    float acc[16];
#pragma unroll
    for (int u = 0; u < 16; ++u) acc[u] = 0.0f;

    for (int ib = 0; ib < 288; ib += 32) {
        __syncthreads();
        {
            int lb = threadIdx.x / 4;           // b 0..63
            int lo = (threadIdx.x % 4) * 8;     // ii 0,8,16,24
            const float* src = x + (size_t)lb * HIDc + i0 + ib + lo;
            float4 a0 = *(const float4*)(src);
            float4 a1 = *(const float4*)(src + 4);
            float tmp[8] = {a0.x, a0.y, a0.z, a0.w, a1.x, a1.y, a1.z, a1.w};
#pragma unroll
            for (int r = 0; r < 8; ++r) s_x[lo + r][lb] = tmp[r];
        }
        __syncthreads();

        for (int ii = 0; ii < 32; ++ii) {
            float wv = w[(size_t)(i0 + ib + ii) * HIDLINc + jBase + j];
            const float4* xp = (const float4*)&s_x[ii][bg * 16];
            float4 x0 = xp[0], x1 = xp[1], x2 = xp[2], x3 = xp[3];
            acc[0]  = fmaf(x0.x, wv, acc[0]);
            acc[1]  = fmaf(x0.y, wv, acc[1]);
            acc[2]  = fmaf(x0.z, wv, acc[2]);
            acc[3]  = fmaf(x0.w, wv, acc[3]);
            acc[4]  = fmaf(x1.x, wv, acc[4]);
            acc[5]  = fmaf(x1.y, wv, acc[5]);
            acc[6]  = fmaf(x1.z, wv, acc[6]);
            acc[7]  = fmaf(x1.w, wv, acc[7]);
            acc[8]  = fmaf(x2.x, wv, acc[8]);
            acc[9]  = fmaf(x2.y, wv, acc[9]);
            acc[10] = fmaf(x2.z, wv, acc[10]);
            acc[11] = fmaf(x2.w, wv, acc[11]);
            acc[12] = fmaf(x3.x, wv, acc[12]);
            acc[13] = fmaf(x3.y, wv, acc[13]);
            acc[14] = fmaf(x3.z, wv, acc[14]);
            acc[15] = fmaf(x3.w, wv, acc[15]);
        }
    }

#pragma unroll
    for (int u = 0; u < 16; ++u) {
        int b = bg * 16 + u;
        partial[((size_t)k * 64 + b) * HIDLINc + jBase + j] = acc[u];
    }
}

__global__ void lin1_reduce(const float* __restrict__ partial,
                            const float* __restrict__ bias,
                            float* __restrict__ x1)
{
    int idx = blockIdx.x * blockDim.x + threadIdx.x;  // 64*512
    if (idx >= 64 * HIDLINc) return;
    int j = idx % HIDLINc;
    float s = 0.0f;
    for (int k = 0; k < KSPLIT; ++k)
        s += partial[(size_t)k * 64 * HIDLINc + idx];
    x1[idx] = fmaxf(s + bias[j], 0.0f);
}

// ---------------------------------------------------------------------------
// lin2: (64,512) @ (512,512) + bias + relu
// ---------------------------------------------------------------------------
__global__ __launch_bounds__(256)
void lin2_k(const float* __restrict__ x1, const float* __restrict__ w,
            const float* __restrict__ bias, float* __restrict__ x2)
{
    const int j  = threadIdx.x % 64;
    const int bl = threadIdx.x / 64;          // 0..3
    const int jBase = blockIdx.x * 64;        // 8
    const int b = blockIdx.y * 4 + bl;        // 16 groups of 4

    __shared__ float s_x[4][HIDLINc];
    for (int idx = threadIdx.x; idx < 4 * HIDLINc; idx += 256)
        s_x[idx / HIDLINc][idx % HIDLINc] =
            x1[(size_t)(blockIdx.y * 4 + idx / HIDLINc) * HIDLINc + idx % HIDLINc];
    __syncthreads();

    float acc = 0.0f;
    for (int i = 0; i < HIDLINc; ++i)
        acc = fmaf(s_x[bl][i], w[(size_t)i * HIDLINc + jBase + j], acc);
    x2[(size_t)b * HIDLINc + jBase + j] = fmaxf(acc + bias[jBase + j], 0.0f);
}

// ---------------------------------------------------------------------------
// lin3: (64,512) @ (512,24) + bias
// ---------------------------------------------------------------------------
__global__ void lin3_k(const float* __restrict__ x2, const float* __restrict__ w,
                       const float* __restrict__ bias, float* __restrict__ prep)
{
    int idx = blockIdx.x * blockDim.x + threadIdx.x;
    if (idx >= 64 * 24) return;
    int j = idx % 24, b = idx / 24;
    float acc = bias[j];
    for (int i = 0; i < HIDLINc; ++i)
        acc = fmaf(x2[(size_t)b * HIDLINc + i], w[i * 24 + j], acc);
    prep[idx] = acc;
}

// ---------------------------------------------------------------------------
// Head: means/sigmas/sample/points.  round = half-to-even (rintf, default RTN)
// ---------------------------------------------------------------------------
__global__ void head_k(const float* __restrict__ prep, const float* __restrict__ noise,
                       float* __restrict__ outMeans, float* __restrict__ outSigmas,
                       int* __restrict__ pts)
{
    int id = blockIdx.x * blockDim.x + threadIdx.x;
    if (id >= BB * Gc) return;
    float m0 = prep[id * 3 + 0];
    float m1 = prep[id * 3 + 1];
    float sraw = prep[id * 3 + 2];
    float s = sraw + 2.0f;                       // SIGMA_BOOST
    // jax.nn.softplus(x) = max(x,0) + log1p(exp(-|x|))
    float sig = fmaxf(s, 0.0f) + log1pf(expf(-fabsf(s)));
    sig += 1e-7f;                                // EPS
    float sg = sig * 95.0f;                      // (HI-1) == (WI-1)
    outMeans[id * 2 + 0] = m0;
    outMeans[id * 2 + 1] = m1;
    outSigmas[id * 2 + 0] = sg;
    outSigmas[id * 2 + 1] = sg;
    float sa0 = m0 + sg * noise[id * 2 + 0];
    float sa1 = m1 + sg * noise[id * 2 + 1];
    float t0 = 1.0f / (1.0f + expf(-sa0));
    float t1 = 1.0f / (1.0f + expf(-sa1));
    pts[id * 2 + 0] = (int)rintf(t0 * 79.0f);    // HI-HG-1
    pts[id * 2 + 1] = (int)rintf(t1 * 79.0f);    // WI-WG-1
}

// ---------------------------------------------------------------------------
// Patch extraction: copy (3,16,16) patch per (b,g)
// ---------------------------------------------------------------------------
__global__ __launch_bounds__(256)
void patch_k(const float* __restrict__ image, const int* __restrict__ pts,
             float* __restrict__ outR)
{
    int id = blockIdx.x;                  // b*G + g
    int b = id / Gc;
    int p0 = pts[id * 2 + 0];
    int p1 = pts[id * 2 + 1];
    for (int idx = threadIdx.x; idx < CIc * HGc * WGc; idx += 256) {
        int c = idx / (HGc * WGc), rem = idx % (HGc * WGc);
        int hh = rem / WGc, ww = rem % WGc;
        outR[(size_t)id * (CIc * HGc * WGc) + idx] =
            image[((size_t)(b * CIc + c) * HIc + p0 + hh) * WIc + p1 + ww];
    }
}

// ---------------------------------------------------------------------------
extern "C" void kernel_launch(void* const* d_in, const int* in_sizes, int n_in,
                              void* d_out, int out_size, void* d_ws, size_t ws_size,
                              hipStream_t stream)
{
    const float* image = (const float*)d_in[0];
    const float* noise = (const float*)d_in[1];
    const float* w1a = (const float*)d_in[2];
    const float* b1a = (const float*)d_in[3];
    const float* w1b = (const float*)d_in[4];
    const float* b1b = (const float*)d_in[5];
    const float* w2a = (const float*)d_in[6];
    const float* b2a = (const float*)d_in[7];
    const float* w2b = (const float*)d_in[8];
    const float* b2b = (const float*)d_in[9];
    const float* w3a = (const float*)d_in[10];
    const float* b3a = (const float*)d_in[11];
    const float* w3b = (const float*)d_in[12];
    const float* b3b = (const float*)d_in[13];
    const float* wl1 = (const float*)d_in[14];
    const float* bl1 = (const float*)d_in[15];
    const float* wl2 = (const float*)d_in[16];
    const float* bl2 = (const float*)d_in[17];
    const float* wl3 = (const float*)d_in[18];
    const float* bl3 = (const float*)d_in[19];

    float* out = (float*)d_out;
    float* ws  = (float*)d_ws;

    // Workspace layout (floats). Two big ping-pong buffers + small extras.
    constexpr size_t BIGF = (size_t)BB * 32 * HIc * WIc;   // 18,874,368 floats
    float* A  = ws;
    float* Bf = ws + BIGF;
    // After conv3b (A consumed), reuse A for linear-stage scratch:
    float* part = A;                          // 64*64*512 = 2,097,152 floats
    float* x1   = A + 3 * 1024 * 1024;        // 32768
    float* x2   = x1 + 64 * HIDLINc;          // 32768
    float* prep = x2 + 64 * HIDLINc;          // 1536
    int*   pts  = (int*)(prep + 1536);        // 1024 ints

    // conv1a: image(64,3,96,96) -> A(64,32,96,96)
    conv3x3_relu<3, 32, 96, 96, 8, 32, 3>
        <<<dim3(36, 64, 1), 256, 0, stream>>>(image, w1a, b1a, A);
    // conv1b: A -> B
    conv3x3_relu<32, 32, 96, 96, 8, 32, 32>
        <<<dim3(36, 64, 1), 256, 0, stream>>>(A, w1b, b1b, Bf);
    // pool 4x4: B -> A (64,32,24,24)
    maxpool_k<32, 96, 96, 4>
        <<<(BB * 32 * 24 * 24 + 255) / 256, 256, 0, stream>>>(Bf, A);
    // conv2a: A -> B (64,64,24,24)
    conv3x3_relu<32, 64, 24, 24, 8, 24, 32>
        <<<dim3(3, 64, 2), 192, 0, stream>>>(A, w2a, b2a, Bf);
    // conv2b: B -> A
    conv3x3_relu<64, 64, 24, 24, 8, 24, 32>
        <<<dim3(3, 64, 2), 192, 0, stream>>>(Bf, w2b, b2b, A);
    // pool 2x2: A -> B (64,64,12,12)
    maxpool_k<64, 24, 24, 2>
        <<<(BB * 64 * 12 * 12 + 255) / 256, 256, 0, stream>>>(A, Bf);
    // conv3a: B -> A (64,128,12,12)
    conv3x3_relu<64, 128, 12, 12, 12, 12, 64>
        <<<dim3(1, 64, 4), 144, 0, stream>>>(Bf, w3a, b3a, A);
    // conv3b: A -> B (64,128,12,12)  == x (64, 18432)
    conv3x3_relu<128, 128, 12, 12, 12, 12, 64>
        <<<dim3(1, 64, 4), 144, 0, stream>>>(A, w3b, b3b, Bf);

    // lin1: x @ wl1 (+bl1, relu) via split-K
    lin1_partial<<<dim3(8, KSPLIT), 256, 0, stream>>>(Bf, wl1, part);
    lin1_reduce<<<(64 * HIDLINc + 255) / 256, 256, 0, stream>>>(part, bl1, x1);
    // lin2
    lin2_k<<<dim3(8, 16), 256, 0, stream>>>(x1, wl2, bl2, x2);
    // lin3 -> prep (64,24)
    lin3_k<<<6, 256, 0, stream>>>(x2, wl3, bl3, prep);
    // head -> means/sigmas into out, pts into ws
    head_k<<<2, 256, 0, stream>>>(prep, noise,
                                  out + (size_t)BB * Gc * CIc * HGc * WGc,
                                  out + (size_t)BB * Gc * CIc * HGc * WGc + BB * Gc * 2,
                                  pts);
    // patch extraction -> out[0 .. 393216)
    patch_k<<<BB * Gc, 256, 0, stream>>>(image, pts, out);
}

// Round 2
// 934.529 us; speedup vs baseline: 1.6922x; 1.6922x over previous
//
#include <hip/hip_runtime.h>
#include <math.h>

// Problem constants
constexpr int BB  = 64;    // batch
constexpr int CIc = 3;     // image channels
constexpr int HIc = 96, WIc = 96;
constexpr int Gc  = 8, HGc = 16, WGc = 16;
constexpr int HIDc = 18432;      // 128*12*12
constexpr int HIDLINc = 512;

// ---------------------------------------------------------------------------
// Direct 3x3 conv (pad=1, stride=1) + bias + ReLU.  (non-split path, conv1*)
// ---------------------------------------------------------------------------
template<int CIN, int COUT, int H, int W, int TH, int TW, int CBLK>
__global__ __launch_bounds__(TH * TW)
void conv3x3_relu(const float* __restrict__ in, const float* __restrict__ wgt,
                  const float* __restrict__ bias, float* __restrict__ out)
{
    constexpr int NTX = W / TW;
    const int tile = blockIdx.x;
    const int tx = tile % NTX, ty = tile / NTX;
    const int b  = blockIdx.y;
    const int coutBase = blockIdx.z * 32;
    const int tid = threadIdx.x;
    const int px = tid % TW, py = tid / TW;
    const int ox = tx * TW, oy = ty * TH;

    __shared__ float s_in[CBLK][TH + 2][TW + 2];

    float acc[32];
#pragma unroll
    for (int oc = 0; oc < 32; ++oc) acc[oc] = bias[coutBase + oc];

    for (int cb = 0; cb < CIN; cb += CBLK) {
        __syncthreads();
        constexpr int TOT = CBLK * (TH + 2) * (TW + 2);
        for (int idx = tid; idx < TOT; idx += TH * TW) {
            int ci  = idx / ((TH + 2) * (TW + 2));
            int rem = idx % ((TH + 2) * (TW + 2));
            int yy = rem / (TW + 2), xx = rem % (TW + 2);
            int gy = oy + yy - 1, gx = ox + xx - 1;
            float v = 0.0f;
            if (gy >= 0 && gy < H && gx >= 0 && gx < W)
                v = in[((size_t)(b * CIN + cb + ci) * H + gy) * W + gx];
            s_in[ci][yy][xx] = v;
        }
        __syncthreads();

        for (int ci = 0; ci < CBLK; ++ci) {
            float v[9];
#pragma unroll
            for (int dy = 0; dy < 3; ++dy)
#pragma unroll
                for (int dx = 0; dx < 3; ++dx)
                    v[dy * 3 + dx] = s_in[ci][py + dy][px + dx];

#pragma unroll
            for (int oc = 0; oc < 32; ++oc) {
                const float* w9 =
                    wgt + ((size_t)(coutBase + oc) * CIN + (cb + ci)) * 9;
#pragma unroll
                for (int k = 0; k < 9; ++k)
                    acc[oc] = fmaf(v[k], w9[k], acc[oc]);
            }
        }
    }

#pragma unroll
    for (int oc = 0; oc < 32; ++oc) {
        out[((size_t)(b * COUT + coutBase + oc) * H + oy + py) * W + ox + px] =
            fmaxf(acc[oc], 0.0f);
    }
}

// ---------------------------------------------------------------------------
// Split-K direct 3x3 conv: each block handles CIN/KS input channels and
// writes bias-free partials.  partial layout: [KS][B][COUT][H][W].
// blockIdx.z = chunk * KS + ks   (chunk = 32-output-channel group)
// Occupancy fix: grids of 768..2048 blocks instead of 256-384.
// ---------------------------------------------------------------------------
template<int CIN, int COUT, int H, int W, int TH, int TW, int KS>
__global__ __launch_bounds__(TH * TW)
void conv3x3_split(const float* __restrict__ in, const float* __restrict__ wgt,
                   float* __restrict__ partial)
{
    constexpr int CBLK = CIN / KS;
    constexpr int NTX = W / TW;
    const int tx = blockIdx.x % NTX, ty = blockIdx.x / NTX;
    const int b  = blockIdx.y;
    const int chunk = blockIdx.z / KS;
    const int ks    = blockIdx.z % KS;
    const int coutBase = chunk * 32;
    const int cinBase  = ks * CBLK;
    const int tid = threadIdx.x;
    const int px = tid % TW, py = tid / TW;
    const int ox = tx * TW, oy = ty * TH;

    __shared__ float s_in[CBLK][TH + 2][TW + 2];

    constexpr int TOT = CBLK * (TH + 2) * (TW + 2);
    for (int idx = tid; idx < TOT; idx += TH * TW) {
        int ci  = idx / ((TH + 2) * (TW + 2));
        int rem = idx % ((TH + 2) * (TW + 2));
        int yy = rem / (TW + 2), xx = rem % (TW + 2);
        int gy = oy + yy - 1, gx = ox + xx - 1;
        float v = 0.0f;
        if (gy >= 0 && gy < H && gx >= 0 && gx < W)
            v = in[((size_t)(b * CIN + cinBase + ci) * H + gy) * W + gx];
        s_in[ci][yy][xx] = v;
    }
    __syncthreads();

    float acc[32];
#pragma unroll
    for (int oc = 0; oc < 32; ++oc) acc[oc] = 0.0f;

    for (int ci = 0; ci < CBLK; ++ci) {
        float v[9];
#pragma unroll
        for (int dy = 0; dy < 3; ++dy)
#pragma unroll
            for (int dx = 0; dx < 3; ++dx)
                v[dy * 3 + dx] = s_in[ci][py + dy][px + dx];

#pragma unroll
        for (int oc = 0; oc < 32; ++oc) {
            const float* w9 =
                wgt + ((size_t)(coutBase + oc) * CIN + (cinBase + ci)) * 9;
#pragma unroll
            for (int k = 0; k < 9; ++k)
                acc[oc] = fmaf(v[k], w9[k], acc[oc]);
        }
    }

#pragma unroll
    for (int oc = 0; oc < 32; ++oc) {
        partial[(((size_t)ks * BB + b) * COUT + coutBase + oc) * (H * W) +
                (oy + py) * W + ox + px] = acc[oc];
    }
}

// Sum split-K partials + bias + ReLU
template<int C, int H, int W, int KS>
__global__ void conv_reduce(const float* __restrict__ partial,
                            const float* __restrict__ bias,
                            float* __restrict__ out)
{
    constexpr int TOTAL = BB * C * H * W;
    int idx = blockIdx.x * blockDim.x + threadIdx.x;
    if (idx >= TOTAL) return;
    int c = (idx / (H * W)) % C;
    float s = bias[c];
#pragma unroll
    for (int k = 0; k < KS; ++k)
        s += partial[(size_t)k * TOTAL + idx];
    out[idx] = fmaxf(s, 0.0f);
}

// ---------------------------------------------------------------------------
// Max pool KxK, stride K
// ---------------------------------------------------------------------------
template<int C, int H, int W, int K>
__global__ void maxpool_k(const float* __restrict__ in, float* __restrict__ out)
{
    constexpr int HO = H / K, WO = W / K;
    int idx = blockIdx.x * blockDim.x + threadIdx.x;
    constexpr int TOTAL = BB * C * HO * WO;
    if (idx >= TOTAL) return;
    int wo = idx % WO; int t = idx / WO;
    int ho = t % HO; t /= HO;
    int c = t % C; int b = t / C;
    const float* p = in + ((size_t)(b * C + c) * H + ho * K) * W + wo * K;
    float m = -INFINITY;
#pragma unroll
    for (int i = 0; i < K; ++i)
#pragma unroll
        for (int j = 0; j < K; ++j)
            m = fmaxf(m, p[i * W + j]);
    out[idx] = m;
}

// ---------------------------------------------------------------------------
// lin1: (64, 18432) @ (18432, 512), split-K partials.
// ---------------------------------------------------------------------------
constexpr int KSPLIT = 64;              // 18432 / 64 = 288 per split
__global__ __launch_bounds__(256)
void lin1_partial(const float* __restrict__ x, const float* __restrict__ w,
                  float* __restrict__ partial)
{
    const int j  = threadIdx.x % 64;
    const int bg = threadIdx.x / 64;          // 0..3
    const int jBase = blockIdx.x * 64;        // 8 tiles of 64
    const int k  = blockIdx.y;                // 0..63
    const int i0 = k * 288;

    __shared__ float s_x[32][64];

    float acc[16];
#pragma unroll
    for (int u = 0; u < 16; ++u) acc[u] = 0.0f;

    for (int ib = 0; ib < 288; ib += 32) {
        __syncthreads();
        {
            int lb = threadIdx.x / 4;           // b 0..63
            int lo = (threadIdx.x % 4) * 8;     // ii 0,8,16,24
            const float* src = x + (size_t)lb * HIDc + i0 + ib + lo;
            float4 a0 = *(const float4*)(src);
            float4 a1 = *(const float4*)(src + 4);
            float tmp[8] = {a0.x, a0.y, a0.z, a0.w, a1.x, a1.y, a1.z, a1.w};
#pragma unroll
            for (int r = 0; r < 8; ++r) s_x[lo + r][lb] = tmp[r];
        }
        __syncthreads();

        for (int ii = 0; ii < 32; ++ii) {
            float wv = w[(size_t)(i0 + ib + ii) * HIDLINc + jBase + j];
            const float4* xp = (const float4*)&s_x[ii][bg * 16];
            float4 x0 = xp[0], x1 = xp[1], x2 = xp[2], x3 = xp[3];
            acc[0]  = fmaf(x0.x, wv, acc[0]);
            acc[1]  = fmaf(x0.y, wv, acc[1]);
            acc[2]  = fmaf(x0.z, wv, acc[2]);
            acc[3]  = fmaf(x0.w, wv, acc[3]);
            acc[4]  = fmaf(x1.x, wv, acc[4]);
            acc[5]  = fmaf(x1.y, wv, acc[5]);
            acc[6]  = fmaf(x1.z, wv, acc[6]);
            acc[7]  = fmaf(x1.w, wv, acc[7]);
            acc[8]  = fmaf(x2.x, wv, acc[8]);
            acc[9]  = fmaf(x2.y, wv, acc[9]);
            acc[10] = fmaf(x2.z, wv, acc[10]);
            acc[11] = fmaf(x2.w, wv, acc[11]);
            acc[12] = fmaf(x3.x, wv, acc[12]);
            acc[13] = fmaf(x3.y, wv, acc[13]);
            acc[14] = fmaf(x3.z, wv, acc[14]);
            acc[15] = fmaf(x3.w, wv, acc[15]);
        }
    }

#pragma unroll
    for (int u = 0; u < 16; ++u) {
        int b = bg * 16 + u;
        partial[((size_t)k * 64 + b) * HIDLINc + jBase + j] = acc[u];
    }
}

__global__ void lin1_reduce(const float* __restrict__ partial,
                            const float* __restrict__ bias,
                            float* __restrict__ x1)
{
    int idx = blockIdx.x * blockDim.x + threadIdx.x;  // 64*512
    if (idx >= 64 * HIDLINc) return;
    int j = idx % HIDLINc;
    float s = 0.0f;
    for (int k = 0; k < KSPLIT; ++k)
        s += partial[(size_t)k * 64 * HIDLINc + idx];
    x1[idx] = fmaxf(s + bias[j], 0.0f);
}

// ---------------------------------------------------------------------------
// lin2: (64,512) @ (512,512) + bias + relu
// ---------------------------------------------------------------------------
__global__ __launch_bounds__(256)
void lin2_k(const float* __restrict__ x1, const float* __restrict__ w,
            const float* __restrict__ bias, float* __restrict__ x2)
{
    const int j  = threadIdx.x % 64;
    const int bl = threadIdx.x / 64;          // 0..3
    const int jBase = blockIdx.x * 64;        // 8
    const int b = blockIdx.y * 4 + bl;        // 16 groups of 4

    __shared__ float s_x[4][HIDLINc];
    for (int idx = threadIdx.x; idx < 4 * HIDLINc; idx += 256)
        s_x[idx / HIDLINc][idx % HIDLINc] =
            x1[(size_t)(blockIdx.y * 4 + idx / HIDLINc) * HIDLINc + idx % HIDLINc];
    __syncthreads();

    float acc = 0.0f;
    for (int i = 0; i < HIDLINc; ++i)
        acc = fmaf(s_x[bl][i], w[(size_t)i * HIDLINc + jBase + j], acc);
    x2[(size_t)b * HIDLINc + jBase + j] = fmaxf(acc + bias[jBase + j], 0.0f);
}

// ---------------------------------------------------------------------------
// lin3: (64,512) @ (512,24) + bias
// ---------------------------------------------------------------------------
__global__ void lin3_k(const float* __restrict__ x2, const float* __restrict__ w,
                       const float* __restrict__ bias, float* __restrict__ prep)
{
    int idx = blockIdx.x * blockDim.x + threadIdx.x;
    if (idx >= 64 * 24) return;
    int j = idx % 24, b = idx / 24;
    float acc = bias[j];
    for (int i = 0; i < HIDLINc; ++i)
        acc = fmaf(x2[(size_t)b * HIDLINc + i], w[i * 24 + j], acc);
    prep[idx] = acc;
}

// ---------------------------------------------------------------------------
// Head: means/sigmas/sample/points.  round = half-to-even (rintf)
// ---------------------------------------------------------------------------
__global__ void head_k(const float* __restrict__ prep, const float* __restrict__ noise,
                       float* __restrict__ outMeans, float* __restrict__ outSigmas,
                       int* __restrict__ pts)
{
    int id = blockIdx.x * blockDim.x + threadIdx.x;
    if (id >= BB * Gc) return;
    float m0 = prep[id * 3 + 0];
    float m1 = prep[id * 3 + 1];
    float sraw = prep[id * 3 + 2];
    float s = sraw + 2.0f;                       // SIGMA_BOOST
    float sig = fmaxf(s, 0.0f) + log1pf(expf(-fabsf(s)));
    sig += 1e-7f;                                // EPS
    float sg = sig * 95.0f;                      // (HI-1) == (WI-1)
    outMeans[id * 2 + 0] = m0;
    outMeans[id * 2 + 1] = m1;
    outSigmas[id * 2 + 0] = sg;
    outSigmas[id * 2 + 1] = sg;
    float sa0 = m0 + sg * noise[id * 2 + 0];
    float sa1 = m1 + sg * noise[id * 2 + 1];
    float t0 = 1.0f / (1.0f + expf(-sa0));
    float t1 = 1.0f / (1.0f + expf(-sa1));
    pts[id * 2 + 0] = (int)rintf(t0 * 79.0f);    // HI-HG-1
    pts[id * 2 + 1] = (int)rintf(t1 * 79.0f);    // WI-WG-1
}

// ---------------------------------------------------------------------------
// Patch extraction: copy (3,16,16) patch per (b,g)
// ---------------------------------------------------------------------------
__global__ __launch_bounds__(256)
void patch_k(const float* __restrict__ image, const int* __restrict__ pts,
             float* __restrict__ outR)
{
    int id = blockIdx.x;                  // b*G + g
    int b = id / Gc;
    int p0 = pts[id * 2 + 0];
    int p1 = pts[id * 2 + 1];
    for (int idx = threadIdx.x; idx < CIc * HGc * WGc; idx += 256) {
        int c = idx / (HGc * WGc), rem = idx % (HGc * WGc);
        int hh = rem / WGc, ww = rem % WGc;
        outR[(size_t)id * (CIc * HGc * WGc) + idx] =
            image[((size_t)(b * CIc + c) * HIc + p0 + hh) * WIc + p1 + ww];
    }
}

// ---------------------------------------------------------------------------
extern "C" void kernel_launch(void* const* d_in, const int* in_sizes, int n_in,
                              void* d_out, int out_size, void* d_ws, size_t ws_size,
                              hipStream_t stream)
{
    const float* image = (const float*)d_in[0];
    const float* noise = (const float*)d_in[1];
    const float* w1a = (const float*)d_in[2];
    const float* b1a = (const float*)d_in[3];
    const float* w1b = (const float*)d_in[4];
    const float* b1b = (const float*)d_in[5];
    const float* w2a = (const float*)d_in[6];
    const float* b2a = (const float*)d_in[7];
    const float* w2b = (const float*)d_in[8];
    const float* b2b = (const float*)d_in[9];
    const float* w3a = (const float*)d_in[10];
    const float* b3a = (const float*)d_in[11];
    const float* w3b = (const float*)d_in[12];
    const float* b3b = (const float*)d_in[13];
    const float* wl1 = (const float*)d_in[14];
    const float* bl1 = (const float*)d_in[15];
    const float* wl2 = (const float*)d_in[16];
    const float* bl2 = (const float*)d_in[17];
    const float* wl3 = (const float*)d_in[18];
    const float* bl3 = (const float*)d_in[19];

    float* out = (float*)d_out;
    float* ws  = (float*)d_ws;

    // Workspace layout (floats): two big regions A,B of 18,874,368 floats.
    constexpr size_t BIGF = (size_t)BB * 32 * HIc * WIc;   // 18,874,368 floats
    constexpr size_t MF = 1u << 20;
    float* A  = ws;
    float* Bf = ws + BIGF;
    // Small tensors inside A (A's conv1a contents are dead after conv1b):
    float* t0   = A;                 // pool1 out      (1,179,648)
    float* t1   = A + 2 * MF;        // conv2a out     (2,359,296)
    float* t2   = A + 5 * MF;        // conv2b out     (2,359,296)
    float* t3   = A + 8 * MF;        // pool2 out        (589,824)
    float* t4   = A + 9 * MF;        // conv3a out     (1,179,648)
    float* t5   = A + 11 * MF;       // conv3b out / x (1,179,648)
    float* part = A + 13 * MF;       // lin1 partials  (2,097,152)
    float* x1   = A + 16 * MF;       // 32768
    float* x2   = x1 + 64 * HIDLINc; // 32768
    float* prep = x2 + 64 * HIDLINc; // 1536
    int*   pts  = (int*)(prep + 2048);

    // conv1a: image(64,3,96,96) -> A(64,32,96,96)   [well-occupied: 2304 blk]
    conv3x3_relu<3, 32, 96, 96, 8, 32, 3>
        <<<dim3(36, 64, 1), 256, 0, stream>>>(image, w1a, b1a, A);
    // conv1b: A -> B
    conv3x3_relu<32, 32, 96, 96, 8, 32, 32>
        <<<dim3(36, 64, 1), 256, 0, stream>>>(A, w1b, b1b, Bf);
    // pool 4x4: B -> t0 (64,32,24,24)   (A's conv1a data now dead)
    maxpool_k<32, 96, 96, 4>
        <<<(BB * 32 * 24 * 24 + 255) / 256, 256, 0, stream>>>(Bf, t0);

    // conv2a: t0 -> partial(B) -> t1 (64,64,24,24); KS=2 -> 768 blocks
    conv3x3_split<32, 64, 24, 24, 8, 24, 2>
        <<<dim3(3, 64, 2 * 2), 192, 0, stream>>>(t0, w2a, Bf);
    conv_reduce<64, 24, 24, 2>
        <<<(BB * 64 * 576 + 255) / 256, 256, 0, stream>>>(Bf, b2a, t1);

    // conv2b: t1 -> partial(B) -> t2; KS=4 -> 1536 blocks
    conv3x3_split<64, 64, 24, 24, 8, 24, 4>
        <<<dim3(3, 64, 2 * 4), 192, 0, stream>>>(t1, w2b, Bf);
    conv_reduce<64, 24, 24, 4>
        <<<(BB * 64 * 576 + 255) / 256, 256, 0, stream>>>(Bf, b2b, t2);

    // pool 2x2: t2 -> t3 (64,64,12,12)
    maxpool_k<64, 24, 24, 2>
        <<<(BB * 64 * 12 * 12 + 255) / 256, 256, 0, stream>>>(t2, t3);

    // conv3a: t3 -> partial(B) -> t4 (64,128,12,12); KS=4 -> 1024 blocks
    conv3x3_split<64, 128, 12, 12, 12, 12, 4>
        <<<dim3(1, 64, 4 * 4), 144, 0, stream>>>(t3, w3a, Bf);
    conv_reduce<128, 12, 12, 4>
        <<<(BB * 128 * 144 + 255) / 256, 256, 0, stream>>>(Bf, b3a, t4);

    // conv3b: t4 -> partial(B) -> t5; KS=8 -> 2048 blocks
    conv3x3_split<128, 128, 12, 12, 12, 12, 8>
        <<<dim3(1, 64, 4 * 8), 144, 0, stream>>>(t4, w3b, Bf);
    conv_reduce<128, 12, 12, 8>
        <<<(BB * 128 * 144 + 255) / 256, 256, 0, stream>>>(Bf, b3b, t5);

    // lin1: x @ wl1 (+bl1, relu) via split-K
    lin1_partial<<<dim3(8, KSPLIT), 256, 0, stream>>>(t5, wl1, part);
    lin1_reduce<<<(64 * HIDLINc + 255) / 256, 256, 0, stream>>>(part, bl1, x1);
    // lin2
    lin2_k<<<dim3(8, 16), 256, 0, stream>>>(x1, wl2, bl2, x2);
    // lin3 -> prep (64,24)
    lin3_k<<<6, 256, 0, stream>>>(x2, wl3, bl3, prep);
    // head -> means/sigmas into out, pts into ws
    head_k<<<2, 256, 0, stream>>>(prep, noise,
                                  out + (size_t)BB * Gc * CIc * HGc * WGc,
                                  out + (size_t)BB * Gc * CIc * HGc * WGc + BB * Gc * 2,
                                  pts);
    // patch extraction -> out[0 .. 393216)
    patch_k<<<BB * Gc, 256, 0, stream>>>(image, pts, out);
}